// Round 3
// baseline (323.722 us; speedup 1.0000x reference)
//
#include <hip/hip_runtime.h>
#include <math.h>

#define NCLS 19
#define MCOMP 5
#define KCOMP (NCLS * MCOMP)   // 95
#define AFEAT 64
#define IGNORE_L 255
#define LOG2PI 1.8378770664093453f
#define NEG_BIG (-1e30f)

// ws layout (float offsets)
#define IV_OFF   0
#define NLIV_OFF (KCOMP * AFEAT)                 // 6080
#define CST_OFF  (2 * KCOMP * AFEAT)             // 12160
#define MT_OFF   (CST_OFF + 96)                  // 12256
#define DR_OFF   (MT_OFF + NCLS * AFEAT)         // 13472
#define ACC_OFF  (DR_OFF + 20)                   // 13492 (sum, cnt)

__global__ void precompute_kernel(const float* __restrict__ mean,
                                  const float* __restrict__ cov,
                                  const float* __restrict__ tmem,
                                  const float* __restrict__ ct,
                                  const float* __restrict__ cs,
                                  float* __restrict__ ws) {
    int blk = blockIdx.x;
    int a = threadIdx.x;  // 64 threads = 1 wave
    if (blk < KCOMP) {
        int k = blk;
        float lo = mean[k * AFEAT + a];
        float c  = cov[k * AFEAT + a];
        float iv = 1.0f / (c * c);
        ws[IV_OFF + k * AFEAT + a]   = iv;
        ws[NLIV_OFF + k * AFEAT + a] = -2.0f * lo * iv;
        float s1 = lo * lo * iv;   // sum loc^2 * inv_var
        float s2 = logf(c);        // sum log(scale)
        for (int off = 32; off > 0; off >>= 1) {
            s1 += __shfl_xor(s1, off, 64);
            s2 += __shfl_xor(s2, off, 64);
        }
        if (a == 0) ws[CST_OFF + k] = AFEAT * LOG2PI + 2.0f * s2 + s1;
    } else if (blk < KCOMP + NCLS) {
        int c = blk - KCOMP;
        const float* p = tmem + ((size_t)c * AFEAT + a) * 100;
        float s = 0.f;
        for (int j = 0; j < 100; ++j) s += p[j];
        s *= 0.01f;
        float n2 = s * s;
        for (int off = 32; off > 0; off >>= 1) n2 += __shfl_xor(n2, off, 64);
        float den = fmaxf(sqrtf(n2), 1e-12f);
        ws[MT_OFF + c * AFEAT + a] = s / den;
    } else {
        if (a < NCLS) {
            float r = ct[a] / cs[a];
            if (isnan(r)) r = 0.f;
            else if (isinf(r)) r = (r > 0.f) ? 3.402823466e38f : -3.402823466e38f;
            ws[DR_OFF + a] = r;
        }
        if (a == 32) { ws[ACC_OFF] = 0.f; ws[ACC_OFF + 1] = 0.f; }
    }
}

__global__ __launch_bounds__(256, 2)
void protogmm_kernel(const float* __restrict__ feat,
                     const int* __restrict__ mask,
                     const float* __restrict__ loc,   // mean, [95,64]
                     const float* __restrict__ wsr,   // read-only weights
                     float* __restrict__ acc) {
    int n = blockIdx.x * 256 + threadIdx.x;
    int b = n >> 16;
    int rem = n & 65535;
    int y = rem >> 8;
    int x = rem & 255;

    // ---- validity from 4x4 label block (majority >= 12/16 of a real class) ----
    const int* mp = mask + (((size_t)b << 10) + ((size_t)y << 2)) * 1024 + ((size_t)x << 2);
    int v[16];
#pragma unroll
    for (int r = 0; r < 4; ++r) {
        int4 q = *reinterpret_cast<const int4*>(mp + (size_t)r * 1024);
        v[r * 4 + 0] = q.x; v[r * 4 + 1] = q.y; v[r * 4 + 2] = q.z; v[r * 4 + 3] = q.w;
    }
    bool valid = false;
#pragma unroll
    for (int i = 0; i < 16; ++i) {
        int cnt = 0;
#pragma unroll
        for (int j = 0; j < 16; ++j) cnt += (v[j] == v[i]) ? 1 : 0;
        if (v[i] != IGNORE_L && cnt >= 12) valid = true;
    }

    // ---- load + l2-normalize feature ----
    float f[AFEAT];
    const float* fp = feat + (size_t)b * AFEAT * 65536 + (y << 8) + x;
    float n2 = 0.f;
#pragma unroll
    for (int a = 0; a < AFEAT; ++a) {
        f[a] = fp[(size_t)a * 65536];
        n2 = fmaf(f[a], f[a], n2);
    }
    float inv = 1.0f / fmaxf(sqrtf(n2), 1e-12f);
#pragma unroll
    for (int a = 0; a < AFEAT; ++a) f[a] *= inv;

    const float* IV  = wsr + IV_OFF;
    const float* NL  = wsr + NLIV_OFF;
    const float* CST = wsr + CST_OFF;
    const float* MT  = wsr + MT_OFF;
    const float* DR  = wsr + DR_OFF;

    // online state
    float gmax = NEG_BIG, smax = NEG_BIG;      // running maxes for lp and simdot
    float best_w = -1.0f;                      // argmax value (in current scale)
    int   best_c = 0;
    float lmax_best = 0.f;                     // logits_max at current best class
    float lseM = NEG_BIG, lseS = 0.f;          // online logsumexp over logits_max

    for (int c = 0; c < NCLS; ++c) {
        // sim dot (f . mean_target[c])
        const float* mt = MT + c * AFEAT;
        float sd = 0.f;
#pragma unroll
        for (int a = 0; a < AFEAT; ++a) sd = fmaf(f[a], mt[a], sd);

        float Lc = NEG_BIG, ssum = 0.f, lmx = NEG_BIG;
        for (int m = 0; m < MCOMP; ++m) {
            int k = c * MCOMP + m;
            const float* ivp = IV + k * AFEAT;
            const float* nlp = NL + k * AFEAT;
            const float* lop = loc + k * AFEAT;
            float am = 0.f, dd = 0.f;
#pragma unroll
            for (int a = 0; a < AFEAT; ++a) {
                float t = fmaf(f[a], ivp[a], nlp[a]);   // x*iv - 2*liv
                am = fmaf(f[a], t, am);                 // x^2*iv - 2*x*liv
                dd = fmaf(f[a], lop[a], dd);            // x . loc
            }
            float lp = -0.5f * (CST[k] + am);
            float lg = dd * 0.01f;                      // / TEMP
            lmx = fmaxf(lmx, lg);
            if (lp > Lc) { ssum = ssum * __expf(Lc - lp) + 1.0f; Lc = lp; }
            else ssum += __expf(lp - Lc);
        }

        // online logsumexp over classes of lmx
        if (lmx > lseM) { lseS = lseS * __expf(lseM - lmx) + 1.0f; lseM = lmx; }
        else lseS += __expf(lmx - lseM);

        // value argmax with running rescale (common softmax denominators cancel)
        float g2  = fmaxf(gmax, Lc);
        float s2m = fmaxf(smax, sd);
        float bw  = best_w * __expf((gmax - g2) + (smax - s2m));
        float w   = DR[c] * __expf(sd - s2m) * ssum * __expf(Lc - g2);
        if (w > bw) { bw = w; best_c = c; lmax_best = lmx; }
        best_w = bw; gmax = g2; smax = s2m;
    }
    (void)best_c;

    float ce = (lseM + __logf(lseS)) - lmax_best;   // -log_softmax[label]

    float cef  = valid ? ce : 0.f;
    float cntf = valid ? 1.f : 0.f;
    for (int off = 32; off > 0; off >>= 1) {
        cef  += __shfl_xor(cef, off, 64);
        cntf += __shfl_xor(cntf, off, 64);
    }
    __shared__ float sred[2][4];
    int wid = threadIdx.x >> 6;
    int lane = threadIdx.x & 63;
    if (lane == 0) { sred[0][wid] = cef; sred[1][wid] = cntf; }
    __syncthreads();
    if (threadIdx.x == 0) {
        float s = sred[0][0] + sred[0][1] + sred[0][2] + sred[0][3];
        float c = sred[1][0] + sred[1][1] + sred[1][2] + sred[1][3];
        atomicAdd(&acc[0], s);
        atomicAdd(&acc[1], c);
    }
}

__global__ void finalize_kernel(const float* __restrict__ acc, float* __restrict__ out) {
    out[0] = acc[0] / fmaxf(acc[1], 1.0f);
}

extern "C" void kernel_launch(void* const* d_in, const int* in_sizes, int n_in,
                              void* d_out, int out_size, void* d_ws, size_t ws_size,
                              hipStream_t stream) {
    const float* feat = (const float*)d_in[0];
    const int*   mask = (const int*)d_in[1];
    const float* mean = (const float*)d_in[2];
    const float* cov  = (const float*)d_in[3];
    const float* tmem = (const float*)d_in[4];
    const float* ct   = (const float*)d_in[5];
    const float* cs   = (const float*)d_in[6];
    float* out = (float*)d_out;
    float* ws  = (float*)d_ws;

    precompute_kernel<<<KCOMP + NCLS + 1, 64, 0, stream>>>(mean, cov, tmem, ct, cs, ws);
    protogmm_kernel<<<1024, 256, 0, stream>>>(feat, mask, mean, ws, ws + ACC_OFF);
    finalize_kernel<<<1, 1, 0, stream>>>(ws + ACC_OFF, out);
}